// Round 6
// baseline (227.637 us; speedup 1.0000x reference)
//
#include <hip/hip_runtime.h>
#include <hip/hip_bf16.h>

#define BB 4
#define CC 256
#define NN 4096
#define GG 8
#define SPLITS 4
#define MBLK 128
#define TKV 32
#define ITERS (NN / SPLITS / TKV)

typedef unsigned short u16;
typedef unsigned int u32;
typedef __bf16 b16x8 __attribute__((ext_vector_type(8)));
typedef float f32x4 __attribute__((ext_vector_type(4)));
typedef u32 u32x4 __attribute__((ext_vector_type(4)));
typedef u32 u32x2 __attribute__((ext_vector_type(2)));
typedef u16 u16x4 __attribute__((ext_vector_type(4)));

// Q pre-scale: C^-0.5 * log2(e) so softmax runs in exp2 domain
#define QSCALE 0.09016844005556021f
#define FMAX 16.0f

// fragment-major chunk: 512 u16 elems = 16 rows x 32 cols in MFMA lane order.
// elem(row, col32) = (quad(col32>>3)*16 + (row&15))*8 + (col32&7)
// A-read gives A[m=row][k=col]; B-read gives B[k=col][n=row].

__device__ __forceinline__ u16 f2bf(float f) {
    u32 u = __builtin_bit_cast(u32, f);
    u = (u + 0x7FFFu + ((u >> 16) & 1u)) >> 16;
    return (u16)u;
}

__device__ __forceinline__ float bf2f(u16 h) {
    return __builtin_bit_cast(float, (u32)h << 16);
}

__device__ __forceinline__ u32 pack_bf2(float a, float b) {
    float2 f; f.x = a; f.y = b;
    __hip_bfloat162 h = __float22bfloat162_rn(f);
    u32 r;
    __builtin_memcpy(&r, &h, 4);
    return r;
}

__device__ __forceinline__ float exp2_raw(float x) {
#if __has_builtin(__builtin_amdgcn_exp2f)
    return __builtin_amdgcn_exp2f(x);
#else
    float r;
    asm("v_exp_f32 %0, %1" : "=v"(r) : "v"(x));
    return r;
#endif
}

__device__ __forceinline__ b16x8 ldfrag(const u16* p) {
    u32x4 v = *reinterpret_cast<const u32x4*>(p);
    return __builtin_bit_cast(b16x8, v);
}

typedef __attribute__((address_space(1))) const unsigned int* gas_p;
typedef __attribute__((address_space(3))) unsigned int* las_p;

__device__ __forceinline__ void g2l(const u16* g, u16* l) {
    __builtin_amdgcn_global_load_lds((gas_p)g, (las_p)l, 16, 0, 0);
}

// ------- 2. Fold GN into QKV weights (frag-major) + frag-major w_proj -------
__global__ void fold_w(const float* __restrict__ w_qkv, const float* __restrict__ w_proj,
                       const float* __restrict__ gamma, const float* __restrict__ beta,
                       const float* __restrict__ stats,
                       u16* __restrict__ wqf, float* __restrict__ biasq,
                       u16* __restrict__ wpf) {
    int o = blockIdx.x;        // 0..767
    int b = blockIdx.y;        // 0..3
    int c = threadIdx.x;       // 0..255
    int g = c >> 5;
    float mu   = stats[(b * GG + g) * 2];
    float rstd = stats[(b * GG + g) * 2 + 1];
    float a  = gamma[c] * rstd;
    float bb = beta[c] - mu * a;
    float w = w_qkv[o * CC + c];
    size_t fe = ((size_t)((o >> 4) * 8 + (c >> 5)) * 64 + ((c & 31) >> 3) * 16 + (o & 15)) * 8 + (c & 7);
    wqf[(size_t)b * 768 * CC + fe] = f2bf(w * a);
    float part = w * bb;
    #pragma unroll
    for (int off = 32; off; off >>= 1) part += __shfl_down(part, off, 64);
    __shared__ float red[4];
    if ((threadIdx.x & 63) == 0) red[threadIdx.x >> 6] = part;
    __syncthreads();
    if (threadIdx.x == 0) biasq[b * 768 + o] = red[0] + red[1] + red[2] + red[3];
    if (b == 0 && o < CC) {
        float wp = w_proj[o * CC + c];
        wpf[fe] = f2bf(wp);
    }
}

// ---- 3. x [B][C][N] fp32 -> xt_frag; fused GroupNorm partial sums ----
__global__ void transpose_x(const float* __restrict__ x, u16* __restrict__ xtf,
                            float* __restrict__ gsum) {
    __shared__ float tile[64][65];
    __shared__ float red[4][4];
    int n0 = blockIdx.x * 64, c0 = blockIdx.y * 64, b = blockIdx.z;
    int t = threadIdx.x;
    int col = t & 63, r0 = t >> 6;
    const float* xp = x + (size_t)b * CC * NN;
    float s0 = 0.f, ss0 = 0.f, s1 = 0.f, ss1 = 0.f;
    #pragma unroll
    for (int i = 0; i < 16; ++i) {
        int row = i * 4 + r0;
        float v = xp[(size_t)(c0 + row) * NN + n0 + col];
        tile[row][col] = v;
        if (i < 8) { s0 += v; ss0 += v * v; } else { s1 += v; ss1 += v * v; }
    }
    #pragma unroll
    for (int off = 32; off; off >>= 1) {
        s0 += __shfl_down(s0, off, 64); ss0 += __shfl_down(ss0, off, 64);
        s1 += __shfl_down(s1, off, 64); ss1 += __shfl_down(ss1, off, 64);
    }
    int wid = t >> 6;
    if ((t & 63) == 0) { red[wid][0] = s0; red[wid][1] = ss0; red[wid][2] = s1; red[wid][3] = ss1; }
    __syncthreads();
    if (t < 2) {
        float s  = red[0][t * 2] + red[1][t * 2] + red[2][t * 2] + red[3][t * 2];
        float ss = red[0][t * 2 + 1] + red[1][t * 2 + 1] + red[2][t * 2 + 1] + red[3][t * 2 + 1];
        int g = (c0 >> 5) + t;
        atomicAdd(&gsum[(b * GG + g) * 2], s);
        atomicAdd(&gsum[(b * GG + g) * 2 + 1], ss);
    }
    int nl = t >> 2;
    int cbq = t & 3;
    int l15 = nl & 15;
    int ntile = (n0 >> 4) + (nl >> 4);
    int kk = (c0 >> 5) + (cbq >> 1);
    u16* ob = xtf + (size_t)b * NN * CC;
    #pragma unroll
    for (int g = 0; g < 4; ++g) {
        int quad = (cbq & 1) * 2 + (g >> 1);
        int j0 = (g & 1) * 4;
        u16x4 v;
        v.x = f2bf(tile[cbq * 16 + g * 4 + 0][nl]);
        v.y = f2bf(tile[cbq * 16 + g * 4 + 1][nl]);
        v.z = f2bf(tile[cbq * 16 + g * 4 + 2][nl]);
        v.w = f2bf(tile[cbq * 16 + g * 4 + 3][nl]);
        *reinterpret_cast<u16x4*>(ob + ((size_t)(ntile * 8 + kk) * 64 + quad * 16 + l15) * 8 + j0) = v;
    }
}

// ---------------- 3b. finalize GN stats ----------------
__global__ void gn_finalize(const float* __restrict__ gsum, float* __restrict__ stats) {
    int i = threadIdx.x;
    if (i < BB * GG) {
        float s = gsum[i * 2], ss = gsum[i * 2 + 1];
        const float inv = 1.f / ((CC / GG) * NN);
        float mu = s * inv;
        float var = ss * inv - mu * mu;
        stats[i * 2] = mu;
        stats[i * 2 + 1] = rsqrtf(var + 1e-5f);
    }
}

// ------- 4. QKV GEMM -> qt_frag, kt_frag (N rows x C cols), v_frag (C rows x N cols) -------
__global__ void __launch_bounds__(256) qkv_gemm(const u16* __restrict__ wqf,
                                                const float* __restrict__ biasq,
                                                const u16* __restrict__ xtf,
                                                u16* __restrict__ qtf, u16* __restrict__ ktf,
                                                u16* __restrict__ vvf) {
    int b = blockIdx.z;
    int o0 = blockIdx.y * 64;
    int n0 = blockIdx.x * 64;
    int lane = threadIdx.x & 63, w = threadIdx.x >> 6;
    int l15 = lane & 15, quad = lane >> 4;
    const u16* A  = wqf + (size_t)b * 768 * CC;
    const u16* Bp = xtf + (size_t)b * NN * CC;
    int otile = (o0 >> 4) + w;
    f32x4 acc[4] = {};
    #pragma unroll
    for (int kk = 0; kk < 8; ++kk) {
        b16x8 af = ldfrag(A + (size_t)(otile * 8 + kk) * 512 + lane * 8);
        #pragma unroll
        for (int nt = 0; nt < 4; ++nt) {
            b16x8 bf = ldfrag(Bp + (size_t)(((n0 >> 4) + nt) * 8 + kk) * 512 + lane * 8);
            acc[nt] = __builtin_amdgcn_mfma_f32_16x16x32_bf16(af, bf, acc[nt], 0, 0, 0);
        }
    }
    int o_base = o0 + w * 16 + quad * 4;
    float bias[4];
    #pragma unroll
    for (int r = 0; r < 4; ++r) bias[r] = biasq[b * 768 + o_base + r];

    if (o0 < 512) {
        int oloc = (o0 < 256) ? o0 : (o0 - 256);
        int kk = (oloc >> 5) + (w >> 1);
        int q_t = (w & 1) * 2 + (quad >> 1);
        int j0 = (quad & 1) * 4;
        u16* dst = ((o0 < 256) ? qtf : ktf) + (size_t)b * NN * CC;
        float sc = (o0 < 256) ? QSCALE : 1.0f;
        #pragma unroll
        for (int nt = 0; nt < 4; ++nt) {
            int n = n0 + nt * 16 + l15;
            int ntile = n >> 4;
            u16x4 pk;
            pk.x = f2bf((acc[nt][0] + bias[0]) * sc);
            pk.y = f2bf((acc[nt][1] + bias[1]) * sc);
            pk.z = f2bf((acc[nt][2] + bias[2]) * sc);
            pk.w = f2bf((acc[nt][3] + bias[3]) * sc);
            *reinterpret_cast<u16x4*>(dst + ((size_t)(ntile * 8 + kk) * 64 + q_t * 16 + l15) * 8 + j0) = pk;
        }
    } else {
        int ctile = ((o0 - 512) + w * 16) >> 4;
        u16* dst = vvf + (size_t)b * NN * CC;
        int jv = l15 & 7;
        #pragma unroll
        for (int nt = 0; nt < 4; ++nt) {
            int kkv = (n0 >> 5) + (nt >> 1);
            int q_v = (nt * 2 + (l15 >> 3)) & 3;
            size_t cb = (size_t)(ctile * (NN / 32) + kkv) * 512;
            #pragma unroll
            for (int r = 0; r < 4; ++r)
                dst[cb + (size_t)(q_v * 16 + quad * 4 + r) * 8 + jv] = f2bf(acc[nt][r] + bias[r]);
        }
    }
}

// ---------------- 5. Flash: M_block=128, LDS-staged K/V, double-buffered ----------------
// 1-D grid, XCD-local swizzle: lin&15 = (b,sp) chunk -> all 32 n-blocks of a
// chunk land on XCDs lin%8 == chunk%8, so KV re-reads hit that XCD's L2.
__global__ void __launch_bounds__(256, 2) flash(const u16* __restrict__ qtf,
                                                const u16* __restrict__ ktf,
                                                const u16* __restrict__ vvf,
                                                u16* __restrict__ po,
                                                float* __restrict__ lp) {
    __shared__ u16 kbuf[2][16 * 512];
    __shared__ u16 vbuf[2][16 * 512];
    __shared__ u16 pbuf[4][32 * 36];
    int lin = blockIdx.x;
    int chunk = lin & 15;
    int nblk = lin >> 4;
    int b = chunk >> 2, sp = chunk & 3;
    int n0 = nblk * MBLK;
    int lane = threadIdx.x & 63, w = threadIdx.x >> 6;
    int l15 = lane & 15, quad = lane >> 4;
    const u16* qb = qtf + (size_t)b * NN * CC;
    const u16* kb = ktf + (size_t)b * NN * CC;
    const u16* vb = vvf + (size_t)b * NN * CC;
    u16* pw = &pbuf[w][0];

    // ones B-fragment (bf16 1.0 x8) for MFMA row-sum of P
    const u32x4 ones32 = {0x3F803F80u, 0x3F803F80u, 0x3F803F80u, 0x3F803F80u};
    const b16x8 vone = __builtin_bit_cast(b16x8, ones32);

    // Q: 32 rows per wave, held in registers
    b16x8 aq[2][8];
    int nt0 = (n0 + w * 32) >> 4;
    #pragma unroll
    for (int a = 0; a < 2; ++a)
        #pragma unroll
        for (int kk = 0; kk < 8; ++kk)
            aq[a][kk] = ldfrag(qb + (size_t)((nt0 + a) * 8 + kk) * 512 + lane * 8);

    f32x4 acco[2][16] = {};
    f32x4 acco_l[2] = {};

    const int m_beg = sp * (NN / SPLITS);

    auto stage = [&](int buf, int m0) {
        int mt0 = m0 >> 4, kv32 = m0 >> 5;
        #pragma unroll
        for (int j = 0; j < 8; ++j) {
            int c = w * 8 + j;
            const u16* g;
            u16* l;
            if (c < 16) {
                g = kb + (size_t)((mt0 + (c >> 3)) * 8 + (c & 7)) * 512;
                l = &kbuf[buf][c * 512];
            } else {
                int ct = c - 16;
                g = vb + (size_t)(ct * (NN / 32) + kv32) * 512;
                l = &vbuf[buf][ct * 512];
            }
            g2l(g + lane * 8, l);
        }
    };

    stage(0, m_beg);
    __syncthreads();
    for (int it = 0; it < ITERS; ++it) {
        int cur = it & 1;
        if (it + 1 < ITERS) stage(cur ^ 1, m_beg + (it + 1) * TKV);
        const u16* kc = &kbuf[cur][0];
        const u16* vc = &vbuf[cur][0];
        // QK: accumulators init to -FMAX (folds softmax max subtraction)
        f32x4 accs[2][2];
        #pragma unroll
        for (int a = 0; a < 2; ++a)
            #pragma unroll
            for (int m = 0; m < 2; ++m) {
                accs[a][m][0] = -FMAX; accs[a][m][1] = -FMAX;
                accs[a][m][2] = -FMAX; accs[a][m][3] = -FMAX;
            }
        #pragma unroll
        for (int kk = 0; kk < 8; ++kk) {
            #pragma unroll
            for (int m = 0; m < 2; ++m) {
                b16x8 bk = ldfrag(kc + (size_t)(m * 8 + kk) * 512 + lane * 8);
                accs[0][m] = __builtin_amdgcn_mfma_f32_16x16x32_bf16(aq[0][kk], bk, accs[0][m], 0, 0, 0);
                accs[1][m] = __builtin_amdgcn_mfma_f32_16x16x32_bf16(aq[1][kk], bk, accs[1][m], 0, 0, 0);
            }
        }
        // P = exp2(S) packed pairwise (m=0,m=1) -> LDS in A-frag layout
        #pragma unroll
        for (int a = 0; a < 2; ++a) {
            #pragma unroll
            for (int r = 0; r < 4; ++r) {
                float e0 = exp2_raw(accs[a][0][r]);
                float e1 = exp2_raw(accs[a][1][r]);
                u32 pk = pack_bf2(e0, e1);
                int row = a * 16 + quad * 4 + r;
                pw[row * 36 + l15]      = (u16)pk;
                pw[row * 36 + 16 + l15] = (u16)(pk >> 16);
            }
        }
        asm volatile("s_waitcnt lgkmcnt(0)" ::: "memory");
        b16x8 ap[2];
        #pragma unroll
        for (int a = 0; a < 2; ++a) {
            ap[a] = ldfrag(pw + (size_t)(a * 16 + l15) * 36 + quad * 8);
            acco_l[a] = __builtin_amdgcn_mfma_f32_16x16x32_bf16(ap[a], vone, acco_l[a], 0, 0, 0);
        }
        #pragma unroll
        for (int ct = 0; ct < 16; ++ct) {
            b16x8 bv = ldfrag(vc + (size_t)ct * 512 + lane * 8);
            acco[0][ct] = __builtin_amdgcn_mfma_f32_16x16x32_bf16(ap[0], bv, acco[0][ct], 0, 0, 0);
            acco[1][ct] = __builtin_amdgcn_mfma_f32_16x16x32_bf16(ap[1], bv, acco[1][ct], 0, 0, 0);
        }
        __syncthreads();
    }
    // epilogue: po in raw C/D-lane chunk layout, u16x4 packed over r
    #pragma unroll
    for (int a = 0; a < 2; ++a) {
        int nchunk = nblk * 8 + w * 2 + a;
        u16* pochunk = po + ((size_t)(sp * BB + b) * 256 + nchunk) * 4096;
        #pragma unroll
        for (int ct = 0; ct < 16; ++ct) {
            u32x2 st;
            st.x = pack_bf2(acco[a][ct][0], acco[a][ct][1]);
            st.y = pack_bf2(acco[a][ct][2], acco[a][ct][3]);
            *reinterpret_cast<u32x2*>(pochunk + (size_t)(ct * 64 + quad * 16 + l15) * 4) = st;
        }
        if (l15 == 0) {
            size_t lbase = (size_t)(sp * BB + b) * NN + n0 + w * 32 + a * 16;
            #pragma unroll
            for (int r = 0; r < 4; ++r) lp[lbase + quad * 4 + r] = acco_l[a][r];
        }
    }
}

// ---- 5b. combine: sum po chunks / sum l -> otf (frag-major), all coalesced ----
__global__ void __launch_bounds__(256) combine(const u16* __restrict__ po,
                                               const float* __restrict__ lp,
                                               u16* __restrict__ otf) {
    int idx = blockIdx.x * 256 + threadIdx.x;   // 131072 threads
    int cg   = idx & 31;          // col group of 8 (c8 = cg*8)
    int quad = (idx >> 5) & 3;    // row quad within 16-row chunk
    int nb   = (idx >> 7) & 255;  // n chunk
    int b    = idx >> 15;
    float acc[4][8] = {};
    float lsum[4] = {};
    #pragma unroll
    for (int s = 0; s < SPLITS; ++s) {
        const u16* src = po + (((size_t)(s * BB + b) * 256 + nb) * 4096)
                       + ((cg >> 1) * 256 + quad * 64 + (cg & 1) * 32);
        u16 s16[32];
        #pragma unroll
        for (int q = 0; q < 4; ++q)
            *reinterpret_cast<u32x4*>(&s16[q * 8]) = *reinterpret_cast<const u32x4*>(src + q * 8);
        #pragma unroll
        for (int r = 0; r < 4; ++r)
            #pragma unroll
            for (int j = 0; j < 8; ++j)
                acc[r][j] += bf2f(s16[j * 4 + r]);
        #pragma unroll
        for (int r = 0; r < 4; ++r)
            lsum[r] += lp[(size_t)(s * BB + b) * NN + nb * 16 + quad * 4 + r];
    }
    u16* dstb = otf + (size_t)b * NN * CC;
    #pragma unroll
    for (int r = 0; r < 4; ++r) {
        float inv = 1.f / lsum[r];
        u16 outv[8];
        #pragma unroll
        for (int j = 0; j < 8; ++j) outv[j] = f2bf(acc[r][j] * inv);
        size_t off = ((size_t)(nb * 8 + (cg >> 2)) * 64 + (cg & 3) * 16 + quad * 4 + r) * 8;
        *reinterpret_cast<u32x4*>(dstb + off) = *reinterpret_cast<const u32x4*>(outv);
    }
}

// ------- 6. proj GEMM + bias + residual ----------------
__global__ void __launch_bounds__(256) proj(const u16* __restrict__ wpf,
                                            const float* __restrict__ b_proj,
                                            const u16* __restrict__ otf,
                                            const float* __restrict__ x,
                                            float* __restrict__ out) {
    int b = blockIdx.z, o0 = blockIdx.y * 64, n0 = blockIdx.x * 64;
    int lane = threadIdx.x & 63, w = threadIdx.x >> 6;
    int l15 = lane & 15, quad = lane >> 4;
    const u16* Bp = otf + (size_t)b * NN * CC;
    int otile = (o0 >> 4) + w;
    f32x4 acc[4] = {};
    #pragma unroll
    for (int kk = 0; kk < 8; ++kk) {
        b16x8 af = ldfrag(wpf + (size_t)(otile * 8 + kk) * 512 + lane * 8);
        #pragma unroll
        for (int nt = 0; nt < 4; ++nt) {
            b16x8 bf = ldfrag(Bp + (size_t)(((n0 >> 4) + nt) * 8 + kk) * 512 + lane * 8);
            acc[nt] = __builtin_amdgcn_mfma_f32_16x16x32_bf16(af, bf, acc[nt], 0, 0, 0);
        }
    }
    int o_base = o0 + w * 16 + quad * 4;
    #pragma unroll
    for (int nt = 0; nt < 4; ++nt) {
        int n = n0 + nt * 16 + l15;
        #pragma unroll
        for (int r = 0; r < 4; ++r) {
            int o = o_base + r;
            size_t idx = ((size_t)(b * CC + o)) * NN + n;
            out[idx] = acc[nt][r] + b_proj[o] + x[idx];
        }
    }
}

extern "C" void kernel_launch(void* const* d_in, const int* in_sizes, int n_in,
                              void* d_out, int out_size, void* d_ws, size_t ws_size,
                              hipStream_t stream) {
    const float* x      = (const float*)d_in[0];
    const float* gamma  = (const float*)d_in[1];
    const float* beta   = (const float*)d_in[2];
    const float* w_qkv  = (const float*)d_in[3];
    const float* w_proj = (const float*)d_in[4];
    const float* b_proj = (const float*)d_in[5];
    float* out = (float*)d_out;

    char* p = (char*)d_ws;
    float* stats = (float*)p; p += 256;
    float* gsum  = (float*)p; p += 256;
    float* biasq = (float*)p; p += (size_t)BB * 768 * sizeof(float);
    u16* wqf = (u16*)p; p += (size_t)BB * 768 * CC * 2;
    u16* wpf = (u16*)p; p += (size_t)CC * CC * 2;
    u16* xtf = (u16*)p; p += (size_t)BB * NN * CC * 2;
    u16* qtf = (u16*)p; p += (size_t)BB * NN * CC * 2;
    u16* ktf = (u16*)p; p += (size_t)BB * NN * CC * 2;
    u16* vvf = (u16*)p; p += (size_t)BB * NN * CC * 2;
    u16* otf = (u16*)p; p += (size_t)BB * NN * CC * 2;
    u16* po = (u16*)p; p += (size_t)SPLITS * BB * NN * CC * 2;
    float* lp = (float*)p; p += (size_t)SPLITS * BB * NN * sizeof(float);
    (void)ws_size; (void)in_sizes; (void)n_in; (void)out_size;

    (void)hipMemsetAsync(gsum, 0, BB * GG * 2 * sizeof(float), stream);
    transpose_x<<<dim3(NN / 64, CC / 64, BB), 256, 0, stream>>>(x, xtf, gsum);
    gn_finalize<<<1, 64, 0, stream>>>(gsum, stats);
    fold_w<<<dim3(768, BB), 256, 0, stream>>>(w_qkv, w_proj, gamma, beta, stats, wqf, biasq, wpf);
    qkv_gemm<<<dim3(NN / 64, 12, BB), 256, 0, stream>>>(wqf, biasq, xtf, qtf, ktf, vvf);
    flash<<<(NN / MBLK) * SPLITS * BB, 256, 0, stream>>>(qtf, ktf, vvf, po, lp);
    combine<<<(BB * NN * CC / 32) / 256, 256, 0, stream>>>(po, lp, otf);
    proj<<<dim3(NN / 64, CC / 64, BB), 256, 0, stream>>>(wpf, b_proj, otf, x, out);
}